// Round 1
// baseline (3578.281 us; speedup 1.0000x reference)
//
#include <hip/hip_runtime.h>

// GCN encoder, restructured:
//   Y1 = x @ W1                      [N,256]x[256,128] -> [N,128]
//   H1 = b1 + spmm(Y1)               (atomic scatter-add over edges, F=128)
//   Y2 = relu(H1) @ W2               [N,128]x[128,64]  -> [N,64]  (relu fused in A-load)
//   out = b2 + spmm(Y2)              (F=64)
// Validity: spmm is linear => spmm(x)@W = spmm(x@W); relu applied after the
// full sum in both formulations.

// ---------------------------------------------------------------- init: out[i,:] = bias
__global__ __launch_bounds__(256) void init_bias_kernel(float* __restrict__ out,
                                                        const float* __restrict__ bias,
                                                        int fmask, size_t total) {
    size_t i = (size_t)blockIdx.x * 256 + threadIdx.x;
    if (i < total) out[i] = bias[i & fmask];
}

// ---------------------------------------------------------------- spmm (atomic)
// One wave per edge. F=128: each lane handles 2 floats (float2). F=64: 1 float.
template <int F>
__global__ __launch_bounds__(256) void spmm_atomic_kernel(const int* __restrict__ rows,
                                                          const int* __restrict__ cols,
                                                          const float* __restrict__ vals,
                                                          const float* __restrict__ Y,
                                                          float* __restrict__ out, int nE) {
    int e = blockIdx.x * 4 + (threadIdx.x >> 6);
    if (e >= nE) return;
    int lane = threadIdx.x & 63;
    int r = rows[e];
    int c = cols[e];
    float v = vals[e];
    if (F == 128) {
        const float2 y = *(const float2*)(Y + (size_t)c * 128 + lane * 2);
        float* op = out + (size_t)r * 128 + lane * 2;
        unsafeAtomicAdd(op, v * y.x);
        unsafeAtomicAdd(op + 1, v * y.y);
    } else {
        float y = Y[(size_t)c * F + lane];
        unsafeAtomicAdd(out + (size_t)r * F + lane, v * y);
    }
}

// ---------------------------------------------------------------- fp32 LDS-tiled GEMM
// C[nrows,NN] = (RELU_IN ? relu(A) : A)[nrows,KK] @ W[KK,NN]
// Block: MT rows. Threads: 256 as (TY=MT/RT) x (TX=NN/CT). Register tile RT x CT.
template <int MT, int NN, int KK, int KT, int RT, int CT, bool RELU_IN>
__global__ __launch_bounds__(256) void gemm_rm_kernel(const float* __restrict__ A,
                                                      const float* __restrict__ W,
                                                      float* __restrict__ C, int nrows) {
    constexpr int TX = NN / CT;
    constexpr int TY = MT / RT;
    static_assert(TX * TY == 256, "thread layout");
    constexpr int APAD = 4;  // pad: A-reads land on 2-way bank aliasing (free on wave64)
    __shared__ float As[MT][KT + APAD];
    __shared__ float Ws[KT][NN];

    const int tid = threadIdx.x;
    const int tx = tid % TX;
    const int ty = tid / TX;
    const int row0 = blockIdx.x * MT;

    float acc[RT][CT];
#pragma unroll
    for (int r = 0; r < RT; ++r)
#pragma unroll
        for (int c = 0; c < CT; ++c) acc[r][c] = 0.f;

    for (int kt = 0; kt < KK; kt += KT) {
        // stage A tile (MT x KT) via float4
        constexpr int A_F4 = MT * KT / 4;
#pragma unroll
        for (int i = tid; i < A_F4; i += 256) {
            int lin = i * 4;
            int m = lin / KT, k = lin % KT;
            int gr = row0 + m;
            float4 v = make_float4(0.f, 0.f, 0.f, 0.f);
            if (gr < nrows) v = *(const float4*)(A + (size_t)gr * KK + kt + k);
            if (RELU_IN) {
                v.x = fmaxf(v.x, 0.f); v.y = fmaxf(v.y, 0.f);
                v.z = fmaxf(v.z, 0.f); v.w = fmaxf(v.w, 0.f);
            }
            As[m][k + 0] = v.x; As[m][k + 1] = v.y;
            As[m][k + 2] = v.z; As[m][k + 3] = v.w;
        }
        // stage W tile (KT x NN) via float4
        constexpr int W_F4 = KT * NN / 4;
#pragma unroll
        for (int i = tid; i < W_F4; i += 256) {
            int lin = i * 4;
            int k = lin / NN, n = lin % NN;
            *(float4*)&Ws[k][n] = *(const float4*)(W + (size_t)(kt + k) * NN + n);
        }
        __syncthreads();

#pragma unroll 4
        for (int k = 0; k < KT; ++k) {
            float a[RT], w[CT];
#pragma unroll
            for (int r = 0; r < RT; ++r) a[r] = As[ty * RT + r][k];
#pragma unroll
            for (int c = 0; c < CT; ++c) w[c] = Ws[k][tx * CT + c];
#pragma unroll
            for (int r = 0; r < RT; ++r)
#pragma unroll
                for (int c = 0; c < CT; ++c) acc[r][c] = fmaf(a[r], w[c], acc[r][c]);
        }
        __syncthreads();
    }

#pragma unroll
    for (int r = 0; r < RT; ++r) {
        int gr = row0 + ty * RT + r;
        if (gr < nrows) {
#pragma unroll
            for (int c = 0; c < CT; c += 4) {
                float4 v = make_float4(acc[r][c], acc[r][c + 1], acc[r][c + 2], acc[r][c + 3]);
                *(float4*)(C + (size_t)gr * NN + tx * CT + c) = v;
            }
        }
    }
}

extern "C" void kernel_launch(void* const* d_in, const int* in_sizes, int n_in,
                              void* d_out, int out_size, void* d_ws, size_t ws_size,
                              hipStream_t stream) {
    const float* x    = (const float*)d_in[0];
    const int*   rows = (const int*)d_in[1];
    const int*   cols = (const int*)d_in[2];
    const float* vals = (const float*)d_in[3];
    const float* W1   = (const float*)d_in[4];
    const float* b1   = (const float*)d_in[5];
    const float* W2   = (const float*)d_in[6];
    const float* b2   = (const float*)d_in[7];
    float* out = (float*)d_out;

    const int nN = in_sizes[0] / 256;  // 100000
    const int nE = in_sizes[1];        // 3200000

    // workspace: Y1 [nN,128] | H1 [nN,128]; Y2 [nN,64] reuses Y1's region
    float* Y1 = (float*)d_ws;
    float* H1 = Y1 + (size_t)nN * 128;
    float* Y2 = Y1;

    const int mblocks = (nN + 63) / 64;
    const int eblocks = (nE + 3) / 4;

    // Y1 = x @ W1
    gemm_rm_kernel<64, 128, 256, 64, 4, 8, false><<<mblocks, 256, 0, stream>>>(x, W1, Y1, nN);

    // H1 = b1 (broadcast)
    size_t totH1 = (size_t)nN * 128;
    init_bias_kernel<<<(int)((totH1 + 255) / 256), 256, 0, stream>>>(H1, b1, 127, totH1);

    // H1 += spmm(Y1)
    spmm_atomic_kernel<128><<<eblocks, 256, 0, stream>>>(rows, cols, vals, Y1, H1, nE);

    // Y2 = relu(H1) @ W2
    gemm_rm_kernel<64, 64, 128, 64, 4, 4, true><<<mblocks, 256, 0, stream>>>(H1, W2, Y2, nN);

    // out = b2 (broadcast)
    size_t totOut = (size_t)nN * 64;
    init_bias_kernel<<<(int)((totOut + 255) / 256), 256, 0, stream>>>(out, b2, 63, totOut);

    // out += spmm(Y2)
    spmm_atomic_kernel<64><<<eblocks, 256, 0, stream>>>(rows, cols, vals, Y2, out, nE);
}

// Round 2
// 1186.444 us; speedup vs baseline: 3.0160x; 3.0160x over previous
//
#include <hip/hip_runtime.h>

// GCN encoder, restructured:
//   Y1 = x @ W1                      [N,256]x[256,128] -> [N,128]
//   H1 = b1 + spmm(Y1)               (CSR, wave-per-row, F=128)
//   Y2 = relu(H1) @ W2               [N,128]x[128,64]  -> [N,64]  (relu fused in A-load)
//   out = b2 + spmm(Y2)              (CSR, F=64)
// CSR is rebuilt every call (harness poisons d_ws): histogram -> scan -> scatter.
// spmm(x)@W == spmm(x@W) (linearity); bias folded into spmm accumulator init.

// ---------------------------------------------------------------- zero ints
__global__ __launch_bounds__(256) void zero_i32_kernel(int* __restrict__ p, int n) {
    int i = blockIdx.x * 256 + threadIdx.x;
    if (i < n) p[i] = 0;
}

// ---------------------------------------------------------------- histogram of rows
__global__ __launch_bounds__(256) void hist_kernel(const int* __restrict__ rows,
                                                   int* __restrict__ cnt, int nE) {
    int e = blockIdx.x * 256 + threadIdx.x;
    if (e < nE) atomicAdd(&cnt[rows[e]], 1);
}

// ---------------------------------------------------------------- exclusive scan (1 block)
// 1024 threads; thread t owns chunk [t*CH, min((t+1)*CH, nN)). Two passes + LDS scan.
__global__ __launch_bounds__(1024) void scan_kernel(const int* __restrict__ cnt,
                                                    int* __restrict__ off,
                                                    int* __restrict__ cursor,
                                                    int nN, int CH) {
    __shared__ int part[1024];
    int t = threadIdx.x;
    int c0 = t * CH;
    int c1 = min(c0 + CH, nN);
    int s = 0;
    for (int i = c0; i < c1; ++i) s += cnt[i];
    part[t] = s;
    __syncthreads();
    // Hillis-Steele inclusive scan in LDS
    for (int d = 1; d < 1024; d <<= 1) {
        int add = (t >= d) ? part[t - d] : 0;
        __syncthreads();
        part[t] += add;
        __syncthreads();
    }
    int run = part[t] - s;  // exclusive prefix for this chunk
    for (int i = c0; i < c1; ++i) {
        off[i] = run;
        cursor[i] = run;
        run += cnt[i];
    }
    if (t == 1023) off[nN] = part[1023];  // total = nE
}

// ---------------------------------------------------------------- scatter edges into CSR order
__global__ __launch_bounds__(256) void scatter_kernel(const int* __restrict__ rows,
                                                      const int* __restrict__ cols,
                                                      const float* __restrict__ vals,
                                                      int* __restrict__ cursor,
                                                      int2* __restrict__ eb, int nE) {
    int e = blockIdx.x * 256 + threadIdx.x;
    if (e < nE) {
        int pos = atomicAdd(&cursor[rows[e]], 1);
        eb[pos] = make_int2(cols[e], __float_as_int(vals[e]));
    }
}

// ---------------------------------------------------------------- CSR spmm: wave per row
// out[row,:] = bias + sum_e val_e * Y[col_e,:]. F=128: float2/lane. F=64: float/lane.
template <int F>
__global__ __launch_bounds__(256) void spmm_csr_kernel(const int* __restrict__ off,
                                                       const int2* __restrict__ eb,
                                                       const float* __restrict__ Y,
                                                       const float* __restrict__ bias,
                                                       float* __restrict__ out, int nN) {
    int row = blockIdx.x * 4 + (threadIdx.x >> 6);
    if (row >= nN) return;
    int lane = threadIdx.x & 63;
    int s = off[row];
    int e1 = off[row + 1];

    float2 acc;
    if (F == 128) acc = make_float2(bias[lane * 2], bias[lane * 2 + 1]);
    else          acc = make_float2(bias[lane], 0.f);

    for (int base = s; base < e1; base += 64) {
        int n = min(64, e1 - base);
        int2 my = (lane < n) ? eb[base + lane] : make_int2(0, 0);
        int j = 0;
        for (; j + 4 <= n; j += 4) {
            int c0 = __shfl(my.x, j + 0), c1 = __shfl(my.x, j + 1);
            int c2 = __shfl(my.x, j + 2), c3 = __shfl(my.x, j + 3);
            float v0 = __int_as_float(__shfl(my.y, j + 0));
            float v1 = __int_as_float(__shfl(my.y, j + 1));
            float v2 = __int_as_float(__shfl(my.y, j + 2));
            float v3 = __int_as_float(__shfl(my.y, j + 3));
            if (F == 128) {
                float2 y0 = *(const float2*)(Y + (size_t)c0 * 128 + lane * 2);
                float2 y1 = *(const float2*)(Y + (size_t)c1 * 128 + lane * 2);
                float2 y2 = *(const float2*)(Y + (size_t)c2 * 128 + lane * 2);
                float2 y3 = *(const float2*)(Y + (size_t)c3 * 128 + lane * 2);
                acc.x = fmaf(v0, y0.x, acc.x); acc.y = fmaf(v0, y0.y, acc.y);
                acc.x = fmaf(v1, y1.x, acc.x); acc.y = fmaf(v1, y1.y, acc.y);
                acc.x = fmaf(v2, y2.x, acc.x); acc.y = fmaf(v2, y2.y, acc.y);
                acc.x = fmaf(v3, y3.x, acc.x); acc.y = fmaf(v3, y3.y, acc.y);
            } else {
                float y0 = Y[(size_t)c0 * 64 + lane];
                float y1 = Y[(size_t)c1 * 64 + lane];
                float y2 = Y[(size_t)c2 * 64 + lane];
                float y3 = Y[(size_t)c3 * 64 + lane];
                acc.x = fmaf(v0, y0, acc.x);
                acc.x = fmaf(v1, y1, acc.x);
                acc.x = fmaf(v2, y2, acc.x);
                acc.x = fmaf(v3, y3, acc.x);
            }
        }
        for (; j < n; ++j) {
            int c = __shfl(my.x, j);
            float v = __int_as_float(__shfl(my.y, j));
            if (F == 128) {
                float2 y = *(const float2*)(Y + (size_t)c * 128 + lane * 2);
                acc.x = fmaf(v, y.x, acc.x);
                acc.y = fmaf(v, y.y, acc.y);
            } else {
                acc.x = fmaf(v, Y[(size_t)c * 64 + lane], acc.x);
            }
        }
    }

    if (F == 128) {
        *(float2*)(out + (size_t)row * 128 + lane * 2) = acc;
    } else {
        out[(size_t)row * 64 + lane] = acc.x;
    }
}

// ---------------------------------------------------------------- fallback atomic path
__global__ __launch_bounds__(256) void init_bias_kernel(float* __restrict__ out,
                                                        const float* __restrict__ bias,
                                                        int fmask, size_t total) {
    size_t i = (size_t)blockIdx.x * 256 + threadIdx.x;
    if (i < total) out[i] = bias[i & fmask];
}

template <int F>
__global__ __launch_bounds__(256) void spmm_atomic_kernel(const int* __restrict__ rows,
                                                          const int* __restrict__ cols,
                                                          const float* __restrict__ vals,
                                                          const float* __restrict__ Y,
                                                          float* __restrict__ out, int nE) {
    int e = blockIdx.x * 4 + (threadIdx.x >> 6);
    if (e >= nE) return;
    int lane = threadIdx.x & 63;
    int r = rows[e];
    int c = cols[e];
    float v = vals[e];
    if (F == 128) {
        const float2 y = *(const float2*)(Y + (size_t)c * 128 + lane * 2);
        float* op = out + (size_t)r * 128 + lane * 2;
        unsafeAtomicAdd(op, v * y.x);
        unsafeAtomicAdd(op + 1, v * y.y);
    } else {
        float y = Y[(size_t)c * F + lane];
        unsafeAtomicAdd(out + (size_t)r * F + lane, v * y);
    }
}

// ---------------------------------------------------------------- fp32 LDS-tiled GEMM
// C[nrows,NN] = (RELU_IN ? relu(A) : A)[nrows,KK] @ W[KK,NN]
template <int MT, int NN, int KK, int KT, int RT, int CT, bool RELU_IN>
__global__ __launch_bounds__(256) void gemm_rm_kernel(const float* __restrict__ A,
                                                      const float* __restrict__ W,
                                                      float* __restrict__ C, int nrows) {
    constexpr int TX = NN / CT;
    constexpr int TY = MT / RT;
    static_assert(TX * TY == 256, "thread layout");
    constexpr int APAD = 4;
    __shared__ float As[MT][KT + APAD];
    __shared__ float Ws[KT][NN];

    const int tid = threadIdx.x;
    const int tx = tid % TX;
    const int ty = tid / TX;
    const int row0 = blockIdx.x * MT;

    float acc[RT][CT];
#pragma unroll
    for (int r = 0; r < RT; ++r)
#pragma unroll
        for (int c = 0; c < CT; ++c) acc[r][c] = 0.f;

    for (int kt = 0; kt < KK; kt += KT) {
        constexpr int A_F4 = MT * KT / 4;
#pragma unroll
        for (int i = tid; i < A_F4; i += 256) {
            int lin = i * 4;
            int m = lin / KT, k = lin % KT;
            int gr = row0 + m;
            float4 v = make_float4(0.f, 0.f, 0.f, 0.f);
            if (gr < nrows) v = *(const float4*)(A + (size_t)gr * KK + kt + k);
            if (RELU_IN) {
                v.x = fmaxf(v.x, 0.f); v.y = fmaxf(v.y, 0.f);
                v.z = fmaxf(v.z, 0.f); v.w = fmaxf(v.w, 0.f);
            }
            As[m][k + 0] = v.x; As[m][k + 1] = v.y;
            As[m][k + 2] = v.z; As[m][k + 3] = v.w;
        }
        constexpr int W_F4 = KT * NN / 4;
#pragma unroll
        for (int i = tid; i < W_F4; i += 256) {
            int lin = i * 4;
            int k = lin / NN, n = lin % NN;
            *(float4*)&Ws[k][n] = *(const float4*)(W + (size_t)(kt + k) * NN + n);
        }
        __syncthreads();

#pragma unroll 4
        for (int k = 0; k < KT; ++k) {
            float a[RT], w[CT];
#pragma unroll
            for (int r = 0; r < RT; ++r) a[r] = As[ty * RT + r][k];
#pragma unroll
            for (int c = 0; c < CT; ++c) w[c] = Ws[k][tx * CT + c];
#pragma unroll
            for (int r = 0; r < RT; ++r)
#pragma unroll
                for (int c = 0; c < CT; ++c) acc[r][c] = fmaf(a[r], w[c], acc[r][c]);
        }
        __syncthreads();
    }

#pragma unroll
    for (int r = 0; r < RT; ++r) {
        int gr = row0 + ty * RT + r;
        if (gr < nrows) {
#pragma unroll
            for (int c = 0; c < CT; c += 4) {
                float4 v = make_float4(acc[r][c], acc[r][c + 1], acc[r][c + 2], acc[r][c + 3]);
                *(float4*)(C + (size_t)gr * NN + tx * CT + c) = v;
            }
        }
    }
}

extern "C" void kernel_launch(void* const* d_in, const int* in_sizes, int n_in,
                              void* d_out, int out_size, void* d_ws, size_t ws_size,
                              hipStream_t stream) {
    const float* x    = (const float*)d_in[0];
    const int*   rows = (const int*)d_in[1];
    const int*   cols = (const int*)d_in[2];
    const float* vals = (const float*)d_in[3];
    const float* W1   = (const float*)d_in[4];
    const float* b1   = (const float*)d_in[5];
    const float* W2   = (const float*)d_in[6];
    const float* b2   = (const float*)d_in[7];
    float* out = (float*)d_out;

    const int nN = in_sizes[0] / 256;  // 100000
    const int nE = in_sizes[1];        // 3200000

    // ws layout: Y1 [nN*128] | H1 [nN*128] | cnt [nN] | off [nN+1] | cursor [nN] | eb [nE int2]
    char* w = (char*)d_ws;
    float* Y1 = (float*)w;                    w += (size_t)nN * 128 * 4;
    float* H1 = (float*)w;                    w += (size_t)nN * 128 * 4;
    float* Y2 = Y1;  // overlays Y1 (only nN*64 needed)
    int*  cnt    = (int*)w;                   w += (size_t)nN * 4;
    int*  off    = (int*)w;                   w += ((size_t)nN + 4) * 4;
    int*  cursor = (int*)w;                   w += (size_t)nN * 4;
    int2* eb     = (int2*)w;                  w += (size_t)nE * 8;
    size_t need = (size_t)(w - (char*)d_ws);

    const int mblocks = (nN + 63) / 64;
    const int nblk    = (nN + 255) / 256;
    const int eblk    = (nE + 255) / 256;
    const int rblocks = (nN + 3) / 4;
    const int eblocks4 = (nE + 3) / 4;

    // Y1 = x @ W1
    gemm_rm_kernel<64, 128, 256, 64, 4, 8, false><<<mblocks, 256, 0, stream>>>(x, W1, Y1, nN);

    if (ws_size >= need) {
        // ---- CSR path ----
        zero_i32_kernel<<<nblk, 256, 0, stream>>>(cnt, nN);
        hist_kernel<<<eblk, 256, 0, stream>>>(rows, cnt, nE);
        scan_kernel<<<1, 1024, 0, stream>>>(cnt, off, cursor, nN, (nN + 1023) / 1024);
        scatter_kernel<<<eblk, 256, 0, stream>>>(rows, cols, vals, cursor, eb, nE);

        // H1 = b1 + spmm(Y1)
        spmm_csr_kernel<128><<<rblocks, 256, 0, stream>>>(off, eb, Y1, b1, H1, nN);
        // Y2 = relu(H1) @ W2
        gemm_rm_kernel<64, 64, 128, 64, 4, 4, true><<<mblocks, 256, 0, stream>>>(H1, W2, Y2, nN);
        // out = b2 + spmm(Y2)
        spmm_csr_kernel<64><<<rblocks, 256, 0, stream>>>(off, eb, Y2, b2, out, nN);
    } else {
        // ---- fallback: atomic path (Round 1) ----
        size_t totH1 = (size_t)nN * 128;
        init_bias_kernel<<<(int)((totH1 + 255) / 256), 256, 0, stream>>>(H1, b1, 127, totH1);
        spmm_atomic_kernel<128><<<eblocks4, 256, 0, stream>>>(rows, cols, vals, Y1, H1, nE);
        gemm_rm_kernel<64, 64, 128, 64, 4, 4, true><<<mblocks, 256, 0, stream>>>(H1, W2, Y2, nN);
        size_t totOut = (size_t)nN * 64;
        init_bias_kernel<<<(int)((totOut + 255) / 256), 256, 0, stream>>>(out, b2, 63, totOut);
        spmm_atomic_kernel<64><<<eblocks4, 256, 0, stream>>>(rows, cols, vals, Y2, out, nE);
    }
}